// Round 7
// baseline (8745.920 us; speedup 1.0000x reference)
//
#include <hip/hip_runtime.h>

typedef unsigned short u16;
typedef unsigned long long u64;
typedef __attribute__((ext_vector_type(8))) short short8;
typedef __attribute__((ext_vector_type(4))) float f32x4;

#define HH 1024
#define BB 64
#define TT 512
#define G3 3072
#define NBLK 192

__device__ __forceinline__ u16 f2b(float f) {
  unsigned u = __float_as_uint(f);
  unsigned r = (u + 0x7fffu + ((u >> 16) & 1u)) >> 16;
  return (u16)r;
}
__device__ __forceinline__ float b2f(u16 h) {
  return __uint_as_float(((unsigned)h) << 16);
}

__device__ __forceinline__ void st_u32_agent(unsigned* p, unsigned v) {
  __hip_atomic_store(p, v, __ATOMIC_RELAXED, __HIP_MEMORY_SCOPE_AGENT);
}
__device__ __forceinline__ unsigned ld_u32_agent(const unsigned* p) {
  return __hip_atomic_load(p, __ATOMIC_RELAXED, __HIP_MEMORY_SCOPE_AGENT);
}

// ---------------- elementwise converts / init ----------------

__global__ void f32_to_bf16_k(const float* __restrict__ s, u16* __restrict__ d, int n) {
  int stride = gridDim.x * blockDim.x * 4;
  for (int i = (blockIdx.x * blockDim.x + threadIdx.x) * 4; i < n; i += stride) {
    float4 v = *(const float4*)(s + i);
    uint2 p;
    p.x = (unsigned)f2b(v.x) | ((unsigned)f2b(v.y) << 16);
    p.y = (unsigned)f2b(v.z) | ((unsigned)f2b(v.w) << 16);
    *(uint2*)(d + i) = p;
  }
}

__global__ void init_h_k(const float* __restrict__ h0in, u16* __restrict__ h0b,
                         u16* __restrict__ h1b) {
  int i = blockIdx.x * blockDim.x + threadIdx.x;
  if (i < BB * HH) {
    h0b[i] = f2b(h0in[i]);
    h1b[i] = f2b(h0in[BB * HH + i]);
  }
}

// ---------------- phase A: xg0 = bf16(x @ W_ih0^T + b_ih0) ----------------

__global__ __launch_bounds__(256) void gemm_xg_k(
    const u16* __restrict__ A, const u16* __restrict__ Wt,
    const float* __restrict__ bias, u16* __restrict__ C) {
  const int bm = blockIdx.x / 24;
  const int bn = blockIdx.x % 24;
  const int m0 = bm * 128, n0 = bn * 128;
  __shared__ __align__(16) u16 al[128 * 40];
  __shared__ __align__(16) u16 bl[128 * 40];
  const int tid = threadIdx.x;
  const int w = tid >> 6, l = tid & 63;
  const int wr = w >> 1, wc = w & 1;
  const int c0 = tid, c1 = tid + 256;
  const int r0 = c0 >> 2, s0 = c0 & 3, r1 = c1 >> 2, s1 = c1 & 3;

  const f32x4 fzero = {0.f, 0.f, 0.f, 0.f};
  f32x4 acc[4][4];
#pragma unroll
  for (int i = 0; i < 4; ++i)
#pragma unroll
    for (int j = 0; j < 4; ++j) acc[i][j] = fzero;

  const u16* a0p = A + (size_t)(m0 + r0) * 1024 + s0 * 8;
  const u16* a1p = A + (size_t)(m0 + r1) * 1024 + s1 * 8;
  const u16* b0p = Wt + (size_t)(n0 + r0) * 1024 + s0 * 8;
  const u16* b1p = Wt + (size_t)(n0 + r1) * 1024 + s1 * 8;

  int4 va0 = *(const int4*)(a0p);
  int4 va1 = *(const int4*)(a1p);
  int4 vb0 = *(const int4*)(b0p);
  int4 vb1 = *(const int4*)(b1p);

  for (int kt = 0; kt < 32; ++kt) {
    __syncthreads();
    *(int4*)&al[r0 * 40 + s0 * 8] = va0;
    *(int4*)&al[r1 * 40 + s1 * 8] = va1;
    *(int4*)&bl[r0 * 40 + s0 * 8] = vb0;
    *(int4*)&bl[r1 * 40 + s1 * 8] = vb1;
    __syncthreads();
    if (kt < 31) {
      va0 = *(const int4*)(a0p + (kt + 1) * 32);
      va1 = *(const int4*)(a1p + (kt + 1) * 32);
      vb0 = *(const int4*)(b0p + (kt + 1) * 32);
      vb1 = *(const int4*)(b1p + (kt + 1) * 32);
    }
    short8 af[4], bf[4];
#pragma unroll
    for (int i = 0; i < 4; ++i)
      af[i] = *(const short8*)&al[(wr * 64 + i * 16 + (l & 15)) * 40 + (l >> 4) * 8];
#pragma unroll
    for (int j = 0; j < 4; ++j)
      bf[j] = *(const short8*)&bl[(wc * 64 + j * 16 + (l & 15)) * 40 + (l >> 4) * 8];
#pragma unroll
    for (int i = 0; i < 4; ++i)
#pragma unroll
      for (int j = 0; j < 4; ++j)
        acc[i][j] = __builtin_amdgcn_mfma_f32_16x16x32_bf16(af[i], bf[j], acc[i][j], 0, 0, 0);
  }

#pragma unroll
  for (int i = 0; i < 4; ++i) {
#pragma unroll
    for (int j = 0; j < 4; ++j) {
      int col = n0 + wc * 64 + j * 16 + (l & 15);
      float bv = bias[col];
#pragma unroll
      for (int q = 0; q < 4; ++q) {
        int row = m0 + wr * 64 + i * 16 + (l >> 4) * 4 + q;
        C[(size_t)row * G3 + col] = f2b(acc[i][j][q] + bv);
      }
    }
  }
}

// ---------------- persistent fused scan, v6 ----------------
// Coherence protocol v3: WRITES of cross-block data stay sc1 (write-through
// -> LLC always fresh). READS of h/xg1 are NORMAL CACHED loads so the ~16
// co-XCD reader blocks share one L2 copy (24 MB/step LLC broadcast -> ~3 MB).
// Staleness handled by ONE acquire-agent fence (buffer_inv) per step after
// the barrier; W lives in LDS (inv-immune), biases in regs. Poll: wave 0
// only (1/4 the flag-line pressure), then syncthreads + all-wave acquire.
//  part0 (blk 0..63):    layer0 step t      (t<=511)
//  part1 (blk 64..127):  xg1 for step t-1   (1<=t<=512)
//  part2 (blk 128..191): layer1 step t-2    (t>=2)

__global__ __launch_bounds__(256, 1) void gru_scan6_k(
    const u16* __restrict__ xg0,
    const u16* __restrict__ whh0, const u16* __restrict__ wih1,
    const u16* __restrict__ whh1,
    const float* __restrict__ bhh0, const float* __restrict__ bih1,
    const float* __restrict__ bhh1,
    const float* __restrict__ h0in,
    u16* __restrict__ h0b, u16* __restrict__ h1b,
    float* __restrict__ xg1, float* __restrict__ out,
    unsigned* __restrict__ flags) {
  const int blk = blockIdx.x;
  const int part = blk >> 6;
  const int sub = blk & 63;
  const int tid = threadIdx.x;
  const int w = tid >> 6, l = tid & 63;
  const int lrow = l & 15;
  const int kb = (l >> 4) * 8;

  const u16* Wsrc;
  int off0, off1, off2;
  if (part == 0) {
    Wsrc = whh0; off0 = sub * 16; off1 = HH + sub * 16; off2 = 2 * HH + sub * 16;
  } else if (part == 1) {
    Wsrc = wih1; off0 = sub * 48; off1 = sub * 48 + 16; off2 = sub * 48 + 32;
  } else {
    Wsrc = whh1; off0 = sub * 16; off1 = HH + sub * 16; off2 = 2 * HH + sub * 16;
  }

  // ---- W slice into LDS: 48 rows x 1024, elem idx ^= (row&7)<<3 ----
  __shared__ __align__(16) u16 wlds[48 * 1024];
  for (int i = tid; i < 6144; i += 256) {
    int r = i >> 7;
    int c = i & 127;
    int g = r >> 4;
    int wrow = (g == 0 ? off0 : (g == 1 ? off1 : off2)) + (r & 15);
    int4 v = *(const int4*)(Wsrc + (size_t)wrow * 1024 + c * 8);
    int idx = r * 1024 + ((c * 8) ^ ((r & 7) << 3));
    *(int4*)&wlds[idx] = v;
  }
  __syncthreads();

  const int j = sub * 16 + lrow;
  const int myrow0 = w * 16 + (l >> 4) * 4;  // rows myrow0..+3 for q=0..3
  const int rr0 = lrow, rr1 = 16 + lrow, rr2 = 32 + lrow;
  const int sx = (lrow & 7) << 3;

  float hreg[4] = {0.f, 0.f, 0.f, 0.f};
  float br = 0.f, bz = 0.f, bn_ = 0.f;
  float bv0 = 0.f, bv1 = 0.f, bv2 = 0.f;
  if (part == 0) {
    br = bhh0[j]; bz = bhh0[HH + j]; bn_ = bhh0[2 * HH + j];
#pragma unroll
    for (int q = 0; q < 4; ++q) hreg[q] = h0in[(myrow0 + q) * HH + j];
  } else if (part == 2) {
    br = bhh1[j]; bz = bhh1[HH + j]; bn_ = bhh1[2 * HH + j];
#pragma unroll
    for (int q = 0; q < 4; ++q) hreg[q] = h0in[BB * HH + (myrow0 + q) * HH + j];
  } else {
    bv0 = bih1[off0 + lrow]; bv1 = bih1[off1 + lrow]; bv2 = bih1[off2 + lrow];
  }

  const u16* Abase = (part == 2) ? h1b : h0b;
  const size_t arow = (size_t)(w * 16 + lrow) * HH + kb;

  for (int t = 0; t <= 513; ++t) {
    const int p0 = t & 1;
    const bool active = (part == 0) ? (t <= 511)
                      : (part == 1) ? (t >= 1 && t <= 512)
                                    : (t >= 2);
    if (active) {
      const u16* Ap = Abase + (size_t)p0 * (BB * HH) + arow;

      // ---- 32-wide A batch: normal cached dwordx4 loads (L2-shared) ----
      short8 ar[32];
#pragma unroll
      for (int ks = 0; ks < 32; ++ks) ar[ks] = *(const short8*)(Ap + ks * 32);

      // ---- overlap: x-gate loads (normal cached) ----
      u16 xrv[4], xzv[4], xnv[4];
      if (part == 0) {
        const u16* xp = xg0 + (size_t)t * BB * G3;
#pragma unroll
        for (int q = 0; q < 4; ++q) {
          const u16* rp = xp + (size_t)(myrow0 + q) * G3;
          xrv[q] = rp[j]; xzv[q] = rp[HH + j]; xnv[q] = rp[2 * HH + j];
        }
      }
      float xg1v[3][4];
      if (part == 2) {
        const float* xp = xg1 + (size_t)p0 * (BB * G3);
#pragma unroll
        for (int q = 0; q < 4; ++q) {
          const float* rp = xp + (size_t)(myrow0 + q) * G3;
          xg1v[0][q] = rp[j];
          xg1v[1][q] = rp[HH + j];
          xg1v[2][q] = rp[2 * HH + j];
        }
      }

      const f32x4 fzero = {0.f, 0.f, 0.f, 0.f};
      f32x4 acc0 = fzero, acc1 = fzero, acc2 = fzero;
#pragma unroll
      for (int ks = 0; ks < 32; ++ks) {
        int ke = kb + ks * 32;
        short8 b0 = *(const short8*)&wlds[rr0 * 1024 + (ke ^ sx)];
        short8 b1 = *(const short8*)&wlds[rr1 * 1024 + (ke ^ sx)];
        short8 b2 = *(const short8*)&wlds[rr2 * 1024 + (ke ^ sx)];
        acc0 = __builtin_amdgcn_mfma_f32_16x16x32_bf16(ar[ks], b0, acc0, 0, 0, 0);
        acc1 = __builtin_amdgcn_mfma_f32_16x16x32_bf16(ar[ks], b1, acc1, 0, 0, 0);
        acc2 = __builtin_amdgcn_mfma_f32_16x16x32_bf16(ar[ks], b2, acc2, 0, 0, 0);
      }

      if (part == 1) {
        float* ox = xg1 + (size_t)(1 - p0) * (BB * G3);
        const int cc0 = off0 + lrow, cc1 = off1 + lrow, cc2 = off2 + lrow;
#pragma unroll
        for (int q = 0; q < 4; ++q) {
          int row = myrow0 + q;
          st_u32_agent((unsigned*)(ox + (size_t)row * G3 + cc0), __float_as_uint(acc0[q] + bv0));
          st_u32_agent((unsigned*)(ox + (size_t)row * G3 + cc1), __float_as_uint(acc1[q] + bv1));
          st_u32_agent((unsigned*)(ox + (size_t)row * G3 + cc2), __float_as_uint(acc2[q] + bv2));
        }
      } else {
        u16* hbn = ((part == 0) ? h0b : h1b) + (size_t)(1 - p0) * (BB * HH);
#pragma unroll
        for (int q = 0; q < 4; ++q) {
          float xr, xz, xn;
          if (part == 0) {
            xr = b2f(xrv[q]); xz = b2f(xzv[q]); xn = b2f(xnv[q]);
          } else {
            xr = xg1v[0][q]; xz = xg1v[1][q]; xn = xg1v[2][q];
          }
          float rr = acc0[q] + br + xr;
          float zz = acc1[q] + bz + xz;
          float nn = acc2[q] + bn_;
          float r = 1.f / (1.f + __expf(-rr));
          float z = 1.f / (1.f + __expf(-zz));
          float n = tanhf(xn + r * nn);
          float hv = (1.f - z) * n + z * hreg[q];
          hreg[q] = hv;
          // pack 2 cols (j even|odd) into u32 via lane-pair shfl, even lane stores
          int hb = (int)f2b(hv);
          int nb = __shfl_xor(hb, 1);
          if ((l & 1) == 0) {
            unsigned pk = (unsigned)(u16)hb | (((unsigned)(u16)nb) << 16);
            st_u32_agent((unsigned*)(hbn + (size_t)(myrow0 + q) * HH + j), pk);
          }
        }
      }
    }

    // ---- grid barrier: flag store + wave0-poll + per-step L2 inv ----
    __syncthreads();  // all waves' sc1 stores vmcnt-drained (ack'd at LLC)
    if (tid == 0) {
      __builtin_amdgcn_fence(__ATOMIC_RELEASE, "workgroup");  // compiler order only
      st_u32_agent(&flags[blk], (unsigned)(t + 1));
    }
    if (tid < 64) {
      const unsigned tgt = (unsigned)(t + 1);
      for (;;) {
        unsigned a0 = ld_u32_agent(&flags[l]);
        unsigned a1 = ld_u32_agent(&flags[l + 64]);
        unsigned a2 = ld_u32_agent(&flags[l + 128]);
        unsigned mn = a0 < a1 ? a0 : a1;
        mn = mn < a2 ? mn : a2;
        if (__all(mn >= tgt)) break;
        __builtin_amdgcn_s_sleep(1);
      }
    }
    __syncthreads();
    // all waves: invalidate L1/L2 so next step's NORMAL loads see LLC-fresh
    __builtin_amdgcn_fence(__ATOMIC_ACQUIRE, "agent");
  }

  // ---- write h_n ----
  if (part == 0) {
#pragma unroll
    for (int q = 0; q < 4; ++q) out[(size_t)(myrow0 + q) * HH + j] = hreg[q];
  } else if (part == 2) {
#pragma unroll
    for (int q = 0; q < 4; ++q) out[BB * HH + (size_t)(myrow0 + q) * HH + j] = hreg[q];
  }
}

// ---------------- host ----------------

extern "C" void kernel_launch(void* const* d_in, const int* in_sizes, int n_in,
                              void* d_out, int out_size, void* d_ws, size_t ws_size,
                              hipStream_t stream) {
  const float* x   = (const float*)d_in[0];
  const float* h0  = (const float*)d_in[1];
  const float* wih = (const float*)d_in[2];
  const float* whh = (const float*)d_in[3];
  const float* bih = (const float*)d_in[4];
  const float* bhh = (const float*)d_in[5];
  float* out = (float*)d_out;

  char* ws = (char*)d_ws;
  size_t off = 0;
  auto alloc = [&](size_t bytes) -> void* {
    void* p = ws + off;
    off += (bytes + 255) & ~(size_t)255;
    return p;
  };
  u16* xbf   = (u16*)alloc((size_t)TT * BB * HH * 2);        // 64 MB
  u16* wihb  = (u16*)alloc((size_t)2 * G3 * HH * 2);         // 12.6 MB
  u16* whhb  = (u16*)alloc((size_t)2 * G3 * HH * 2);         // 12.6 MB
  u16* xg0   = (u16*)alloc((size_t)TT * BB * G3 * 2);        // 201 MB
  u16* h0b   = (u16*)alloc((size_t)2 * BB * HH * 2);
  u16* h1b   = (u16*)alloc((size_t)2 * BB * HH * 2);
  float* xg1 = (float*)alloc((size_t)2 * BB * G3 * 4);
  unsigned* flags = (unsigned*)alloc(NBLK * 4);

  hipMemsetAsync(flags, 0, NBLK * 4, stream);
  f32_to_bf16_k<<<2048, 256, 0, stream>>>(x, xbf, TT * BB * HH);
  f32_to_bf16_k<<<512, 256, 0, stream>>>(wih, wihb, 2 * G3 * HH);
  f32_to_bf16_k<<<512, 256, 0, stream>>>(whh, whhb, 2 * G3 * HH);
  init_h_k<<<256, 256, 0, stream>>>(h0, h0b, h1b);

  gemm_xg_k<<<6144, 256, 0, stream>>>(xbf, wihb, bih, xg0);

  gru_scan6_k<<<NBLK, 256, 0, stream>>>(xg0,
                                        whhb, wihb + (size_t)G3 * HH, whhb + (size_t)G3 * HH,
                                        bhh, bih + G3, bhh + G3, h0,
                                        h0b, h1b, xg1, out, flags);
}

// Round 8
// 6450.767 us; speedup vs baseline: 1.3558x; 1.3558x over previous
//
#include <hip/hip_runtime.h>

typedef unsigned short u16;
typedef unsigned long long u64;
typedef __attribute__((ext_vector_type(8))) short short8;
typedef __attribute__((ext_vector_type(4))) float f32x4;

#define HH 1024
#define BB 64
#define TT 512
#define G3 3072
#define NBLK 192
#define NS 513                 // h time-slots (renamed buffers)
#define SLOT (BB * HH)         // elems per h slot

__device__ __forceinline__ u16 f2b(float f) {
  unsigned u = __float_as_uint(f);
  unsigned r = (u + 0x7fffu + ((u >> 16) & 1u)) >> 16;
  return (u16)r;
}
__device__ __forceinline__ float b2f(u16 h) {
  return __uint_as_float(((unsigned)h) << 16);
}

__device__ __forceinline__ void st_u32_agent(unsigned* p, unsigned v) {
  __hip_atomic_store(p, v, __ATOMIC_RELAXED, __HIP_MEMORY_SCOPE_AGENT);
}
__device__ __forceinline__ unsigned ld_u32_agent(const unsigned* p) {
  return __hip_atomic_load(p, __ATOMIC_RELAXED, __HIP_MEMORY_SCOPE_AGENT);
}

// ---------------- elementwise converts / init ----------------

__global__ void f32_to_bf16_k(const float* __restrict__ s, u16* __restrict__ d, int n) {
  int stride = gridDim.x * blockDim.x * 4;
  for (int i = (blockIdx.x * blockDim.x + threadIdx.x) * 4; i < n; i += stride) {
    float4 v = *(const float4*)(s + i);
    uint2 p;
    p.x = (unsigned)f2b(v.x) | ((unsigned)f2b(v.y) << 16);
    p.y = (unsigned)f2b(v.z) | ((unsigned)f2b(v.w) << 16);
    *(uint2*)(d + i) = p;
  }
}

__global__ void init_h_k(const float* __restrict__ h0in, u16* __restrict__ hbuf0,
                         u16* __restrict__ hbuf1) {
  int i = blockIdx.x * blockDim.x + threadIdx.x;
  if (i < BB * HH) {
    hbuf0[i] = f2b(h0in[i]);            // slot 0 = H0(0)
    hbuf1[i] = f2b(h0in[BB * HH + i]);  // slot 0 = H1(0)
  }
}

// ---------------- phase A: xg0 = bf16(x @ W_ih0^T + b_ih0) ----------------

__global__ __launch_bounds__(256) void gemm_xg_k(
    const u16* __restrict__ A, const u16* __restrict__ Wt,
    const float* __restrict__ bias, u16* __restrict__ C) {
  const int bm = blockIdx.x / 24;
  const int bn = blockIdx.x % 24;
  const int m0 = bm * 128, n0 = bn * 128;
  __shared__ __align__(16) u16 al[128 * 40];
  __shared__ __align__(16) u16 bl[128 * 40];
  const int tid = threadIdx.x;
  const int w = tid >> 6, l = tid & 63;
  const int wr = w >> 1, wc = w & 1;
  const int c0 = tid, c1 = tid + 256;
  const int r0 = c0 >> 2, s0 = c0 & 3, r1 = c1 >> 2, s1 = c1 & 3;

  const f32x4 fzero = {0.f, 0.f, 0.f, 0.f};
  f32x4 acc[4][4];
#pragma unroll
  for (int i = 0; i < 4; ++i)
#pragma unroll
    for (int j = 0; j < 4; ++j) acc[i][j] = fzero;

  const u16* a0p = A + (size_t)(m0 + r0) * 1024 + s0 * 8;
  const u16* a1p = A + (size_t)(m0 + r1) * 1024 + s1 * 8;
  const u16* b0p = Wt + (size_t)(n0 + r0) * 1024 + s0 * 8;
  const u16* b1p = Wt + (size_t)(n0 + r1) * 1024 + s1 * 8;

  int4 va0 = *(const int4*)(a0p);
  int4 va1 = *(const int4*)(a1p);
  int4 vb0 = *(const int4*)(b0p);
  int4 vb1 = *(const int4*)(b1p);

  for (int kt = 0; kt < 32; ++kt) {
    __syncthreads();
    *(int4*)&al[r0 * 40 + s0 * 8] = va0;
    *(int4*)&al[r1 * 40 + s1 * 8] = va1;
    *(int4*)&bl[r0 * 40 + s0 * 8] = vb0;
    *(int4*)&bl[r1 * 40 + s1 * 8] = vb1;
    __syncthreads();
    if (kt < 31) {
      va0 = *(const int4*)(a0p + (kt + 1) * 32);
      va1 = *(const int4*)(a1p + (kt + 1) * 32);
      vb0 = *(const int4*)(b0p + (kt + 1) * 32);
      vb1 = *(const int4*)(b1p + (kt + 1) * 32);
    }
    short8 af[4], bf[4];
#pragma unroll
    for (int i = 0; i < 4; ++i)
      af[i] = *(const short8*)&al[(wr * 64 + i * 16 + (l & 15)) * 40 + (l >> 4) * 8];
#pragma unroll
    for (int j = 0; j < 4; ++j)
      bf[j] = *(const short8*)&bl[(wc * 64 + j * 16 + (l & 15)) * 40 + (l >> 4) * 8];
#pragma unroll
    for (int i = 0; i < 4; ++i)
#pragma unroll
      for (int j = 0; j < 4; ++j)
        acc[i][j] = __builtin_amdgcn_mfma_f32_16x16x32_bf16(af[i], bf[j], acc[i][j], 0, 0, 0);
  }

#pragma unroll
  for (int i = 0; i < 4; ++i) {
#pragma unroll
    for (int j = 0; j < 4; ++j) {
      int col = n0 + wc * 64 + j * 16 + (l & 15);
      float bv = bias[col];
#pragma unroll
      for (int q = 0; q < 4; ++q) {
        int row = m0 + wr * 64 + i * 16 + (l >> 4) * 4 + q;
        C[(size_t)row * G3 + col] = f2b(acc[i][j][q] + bv);
      }
    }
  }
}

// ---------------- persistent fused scan, v7: renamed h buffers ----------------
// h state for step t lives at hbuf[t] (fresh address every step). A never-
// before-read address cannot be stale in L1/L2 -> h reads are NORMAL CACHED
// loads (each XCD fetches 128 KB once from LLC; ~16 co-XCD blocks L2-hit).
// Writes stay sc1 (write-through -> LLC fresh). NO fences/inv in the loop;
// ONE agent-acquire at kernel start kills stale lines from prior graph
// replays. xg1 stays parity-buffered point-to-point sc1 (low volume).
//  part0 (blk 0..63):    layer0 step t      (t<=511)  reads hbuf0[t],  writes hbuf0[t+1]
//  part1 (blk 64..127):  xg1 for step t-1   (1<=t<=512) reads hbuf0[t]
//  part2 (blk 128..191): layer1 step t-2    (t>=2)     reads hbuf1[t-2], writes hbuf1[t-1]

__global__ __launch_bounds__(256, 1) void gru_scan7_k(
    const u16* __restrict__ xg0,
    const u16* __restrict__ whh0, const u16* __restrict__ wih1,
    const u16* __restrict__ whh1,
    const float* __restrict__ bhh0, const float* __restrict__ bih1,
    const float* __restrict__ bhh1,
    const float* __restrict__ h0in,
    u16* __restrict__ hbuf0, u16* __restrict__ hbuf1,
    float* __restrict__ xg1, float* __restrict__ out,
    unsigned* __restrict__ flags) {
  const int blk = blockIdx.x;
  const int part = blk >> 6;
  const int sub = blk & 63;
  const int tid = threadIdx.x;
  const int w = tid >> 6, l = tid & 63;
  const int lrow = l & 15;
  const int kb = (l >> 4) * 8;

  const u16* Wsrc;
  int off0, off1, off2;
  if (part == 0) {
    Wsrc = whh0; off0 = sub * 16; off1 = HH + sub * 16; off2 = 2 * HH + sub * 16;
  } else if (part == 1) {
    Wsrc = wih1; off0 = sub * 48; off1 = sub * 48 + 16; off2 = sub * 48 + 32;
  } else {
    Wsrc = whh1; off0 = sub * 16; off1 = HH + sub * 16; off2 = 2 * HH + sub * 16;
  }

  // ---- W slice into LDS: 48 rows x 1024, elem idx ^= (row&7)<<3 ----
  __shared__ __align__(16) u16 wlds[48 * 1024];
  for (int i = tid; i < 6144; i += 256) {
    int r = i >> 7;
    int c = i & 127;
    int g = r >> 4;
    int wrow = (g == 0 ? off0 : (g == 1 ? off1 : off2)) + (r & 15);
    int4 v = *(const int4*)(Wsrc + (size_t)wrow * 1024 + c * 8);
    int idx = r * 1024 + ((c * 8) ^ ((r & 7) << 3));
    *(int4*)&wlds[idx] = v;
  }
  __syncthreads();
  // one-time: kill L1/L2 lines cached during PREVIOUS graph replay (W already
  // safe in LDS; biases/hreg in registers). No cache ops inside the t-loop.
  __builtin_amdgcn_fence(__ATOMIC_ACQUIRE, "agent");

  const int j = sub * 16 + lrow;
  const int myrow0 = w * 16 + (l >> 4) * 4;  // rows myrow0..+3 for q=0..3
  const int rr0 = lrow, rr1 = 16 + lrow, rr2 = 32 + lrow;
  const int sx = (lrow & 7) << 3;

  float hreg[4] = {0.f, 0.f, 0.f, 0.f};
  float br = 0.f, bz = 0.f, bn_ = 0.f;
  float bv0 = 0.f, bv1 = 0.f, bv2 = 0.f;
  if (part == 0) {
    br = bhh0[j]; bz = bhh0[HH + j]; bn_ = bhh0[2 * HH + j];
#pragma unroll
    for (int q = 0; q < 4; ++q) hreg[q] = h0in[(myrow0 + q) * HH + j];
  } else if (part == 2) {
    br = bhh1[j]; bz = bhh1[HH + j]; bn_ = bhh1[2 * HH + j];
#pragma unroll
    for (int q = 0; q < 4; ++q) hreg[q] = h0in[BB * HH + (myrow0 + q) * HH + j];
  } else {
    bv0 = bih1[off0 + lrow]; bv1 = bih1[off1 + lrow]; bv2 = bih1[off2 + lrow];
  }

  const size_t arow = (size_t)(w * 16 + lrow) * HH + kb;

  for (int t = 0; t <= 513; ++t) {
    const int p0 = t & 1;
    const bool active = (part == 0) ? (t <= 511)
                      : (part == 1) ? (t >= 1 && t <= 512)
                                    : (t >= 2);
    if (active) {
      // renamed slot: part0/1 read hbuf0[t]; part2 reads hbuf1[t-2]
      const u16* Ap = ((part == 2) ? hbuf1 + (size_t)(t - 2) * SLOT
                                   : hbuf0 + (size_t)t * SLOT) + arow;

      // ---- 32-wide A batch: NORMAL cached dwordx4 loads (L2-shared) ----
      short8 ar[32];
#pragma unroll
      for (int ks = 0; ks < 32; ++ks) ar[ks] = *(const short8*)(Ap + ks * 32);

      // ---- overlap: x-gate loads ----
      u16 xrv[4], xzv[4], xnv[4];
      if (part == 0) {
        const u16* xp = xg0 + (size_t)t * BB * G3;
#pragma unroll
        for (int q = 0; q < 4; ++q) {
          const u16* rp = xp + (size_t)(myrow0 + q) * G3;
          xrv[q] = rp[j]; xzv[q] = rp[HH + j]; xnv[q] = rp[2 * HH + j];
        }
      }
      float xg1v[3][4];
      if (part == 2) {
        const float* xp = xg1 + (size_t)p0 * (BB * G3);
#pragma unroll
        for (int q = 0; q < 4; ++q) {
          const float* rp = xp + (size_t)(myrow0 + q) * G3;
          xg1v[0][q] = __uint_as_float(ld_u32_agent((const unsigned*)(rp + j)));
          xg1v[1][q] = __uint_as_float(ld_u32_agent((const unsigned*)(rp + HH + j)));
          xg1v[2][q] = __uint_as_float(ld_u32_agent((const unsigned*)(rp + 2 * HH + j)));
        }
      }

      const f32x4 fzero = {0.f, 0.f, 0.f, 0.f};
      f32x4 acc0 = fzero, acc1 = fzero, acc2 = fzero;
#pragma unroll
      for (int ks = 0; ks < 32; ++ks) {
        int ke = kb + ks * 32;
        short8 b0 = *(const short8*)&wlds[rr0 * 1024 + (ke ^ sx)];
        short8 b1 = *(const short8*)&wlds[rr1 * 1024 + (ke ^ sx)];
        short8 b2 = *(const short8*)&wlds[rr2 * 1024 + (ke ^ sx)];
        acc0 = __builtin_amdgcn_mfma_f32_16x16x32_bf16(ar[ks], b0, acc0, 0, 0, 0);
        acc1 = __builtin_amdgcn_mfma_f32_16x16x32_bf16(ar[ks], b1, acc1, 0, 0, 0);
        acc2 = __builtin_amdgcn_mfma_f32_16x16x32_bf16(ar[ks], b2, acc2, 0, 0, 0);
      }

      if (part == 1) {
        float* ox = xg1 + (size_t)(1 - p0) * (BB * G3);
        const int cc0 = off0 + lrow, cc1 = off1 + lrow, cc2 = off2 + lrow;
#pragma unroll
        for (int q = 0; q < 4; ++q) {
          int row = myrow0 + q;
          st_u32_agent((unsigned*)(ox + (size_t)row * G3 + cc0), __float_as_uint(acc0[q] + bv0));
          st_u32_agent((unsigned*)(ox + (size_t)row * G3 + cc1), __float_as_uint(acc1[q] + bv1));
          st_u32_agent((unsigned*)(ox + (size_t)row * G3 + cc2), __float_as_uint(acc2[q] + bv2));
        }
      } else {
        u16* hbn = (part == 0) ? hbuf0 + (size_t)(t + 1) * SLOT
                               : hbuf1 + (size_t)(t - 1) * SLOT;
#pragma unroll
        for (int q = 0; q < 4; ++q) {
          float xr, xz, xn;
          if (part == 0) {
            xr = b2f(xrv[q]); xz = b2f(xzv[q]); xn = b2f(xnv[q]);
          } else {
            xr = xg1v[0][q]; xz = xg1v[1][q]; xn = xg1v[2][q];
          }
          float rr = acc0[q] + br + xr;
          float zz = acc1[q] + bz + xz;
          float nn = acc2[q] + bn_;
          float r = 1.f / (1.f + __expf(-rr));
          float z = 1.f / (1.f + __expf(-zz));
          float n = tanhf(xn + r * nn);
          float hv = (1.f - z) * n + z * hreg[q];
          hreg[q] = hv;
          // pack 2 cols (j even|odd) into u32 via lane-pair shfl, even lane stores
          int hb = (int)f2b(hv);
          int nb = __shfl_xor(hb, 1);
          if ((l & 1) == 0) {
            unsigned pk = (unsigned)(u16)hb | (((unsigned)(u16)nb) << 16);
            st_u32_agent((unsigned*)(hbn + (size_t)(myrow0 + q) * HH + j), pk);
          }
        }
      }
    }

    // ---- grid barrier: flag store (sc1) + wave0-only poll, no cache ops ----
    __syncthreads();  // all waves' sc1 stores vmcnt-drained (ack'd at LLC)
    if (tid == 0) {
      __builtin_amdgcn_fence(__ATOMIC_RELEASE, "workgroup");  // compiler order only
      st_u32_agent(&flags[blk], (unsigned)(t + 1));
    }
    if (tid < 64) {
      const unsigned tgt = (unsigned)(t + 1);
      for (;;) {
        unsigned a0 = ld_u32_agent(&flags[l]);
        unsigned a1 = ld_u32_agent(&flags[l + 64]);
        unsigned a2 = ld_u32_agent(&flags[l + 128]);
        unsigned mn = a0 < a1 ? a0 : a1;
        mn = mn < a2 ? mn : a2;
        if (__all(mn >= tgt)) break;
        __builtin_amdgcn_s_sleep(1);
      }
    }
    __syncthreads();
    __builtin_amdgcn_fence(__ATOMIC_ACQUIRE, "workgroup");  // compiler order only
  }

  // ---- write h_n ----
  if (part == 0) {
#pragma unroll
    for (int q = 0; q < 4; ++q) out[(size_t)(myrow0 + q) * HH + j] = hreg[q];
  } else if (part == 2) {
#pragma unroll
    for (int q = 0; q < 4; ++q) out[BB * HH + (size_t)(myrow0 + q) * HH + j] = hreg[q];
  }
}

// ---------------- host ----------------

extern "C" void kernel_launch(void* const* d_in, const int* in_sizes, int n_in,
                              void* d_out, int out_size, void* d_ws, size_t ws_size,
                              hipStream_t stream) {
  const float* x   = (const float*)d_in[0];
  const float* h0  = (const float*)d_in[1];
  const float* wih = (const float*)d_in[2];
  const float* whh = (const float*)d_in[3];
  const float* bih = (const float*)d_in[4];
  const float* bhh = (const float*)d_in[5];
  float* out = (float*)d_out;

  char* ws = (char*)d_ws;
  size_t off = 0;
  auto alloc = [&](size_t bytes) -> void* {
    void* p = ws + off;
    off += (bytes + 255) & ~(size_t)255;
    return p;
  };
  u16* xg0   = (u16*)alloc((size_t)TT * BB * G3 * 2);        // 193 MB
  u16* wihb  = (u16*)alloc((size_t)2 * G3 * HH * 2);         // 12.6 MB
  u16* whhb  = (u16*)alloc((size_t)2 * G3 * HH * 2);         // 12.6 MB
  // union: xbf (64 MB, dead after gemm) overlaid by hbuf0/hbuf1 (134.5 MB)
  size_t hbytes = (size_t)2 * NS * SLOT * 2;
  size_t xbytes = (size_t)TT * BB * HH * 2;
  char* un = (char*)alloc(hbytes > xbytes ? hbytes : xbytes);
  u16* xbf   = (u16*)un;
  u16* hbuf0 = (u16*)un;
  u16* hbuf1 = hbuf0 + (size_t)NS * SLOT;
  float* xg1 = (float*)alloc((size_t)2 * BB * G3 * 4);
  unsigned* flags = (unsigned*)alloc(NBLK * 4);

  hipMemsetAsync(flags, 0, NBLK * 4, stream);
  f32_to_bf16_k<<<2048, 256, 0, stream>>>(x, xbf, TT * BB * HH);
  f32_to_bf16_k<<<512, 256, 0, stream>>>(wih, wihb, 2 * G3 * HH);
  f32_to_bf16_k<<<512, 256, 0, stream>>>(whh, whhb, 2 * G3 * HH);

  gemm_xg_k<<<6144, 256, 0, stream>>>(xbf, wihb, bih, xg0);

  // init h AFTER gemm: hbuf aliases xbf
  init_h_k<<<256, 256, 0, stream>>>(h0, hbuf0, hbuf1);

  gru_scan7_k<<<NBLK, 256, 0, stream>>>(xg0,
                                        whhb, wihb + (size_t)G3 * HH, whhb + (size_t)G3 * HH,
                                        bhh, bih + G3, bhh + G3, h0,
                                        hbuf0, hbuf1, xg1, out, flags);
}

// Round 9
// 5467.089 us; speedup vs baseline: 1.5997x; 1.1799x over previous
//
#include <hip/hip_runtime.h>

typedef unsigned short u16;
typedef unsigned long long u64;
typedef __attribute__((ext_vector_type(8))) short short8;
typedef __attribute__((ext_vector_type(4))) float f32x4;

#define HH 1024
#define BB 64
#define TT 512
#define G3 3072
#define NBLK 192
#define NS 513                 // h time-slots (renamed buffers)
#define SLOT (BB * HH)         // elems per h slot
#define FSTRIDE 32             // flag padding: one 128B line per block

__device__ __forceinline__ u16 f2b(float f) {
  unsigned u = __float_as_uint(f);
  unsigned r = (u + 0x7fffu + ((u >> 16) & 1u)) >> 16;
  return (u16)r;
}
__device__ __forceinline__ float b2f(u16 h) {
  return __uint_as_float(((unsigned)h) << 16);
}

__device__ __forceinline__ void st_u32_agent(unsigned* p, unsigned v) {
  __hip_atomic_store(p, v, __ATOMIC_RELAXED, __HIP_MEMORY_SCOPE_AGENT);
}
__device__ __forceinline__ unsigned ld_u32_agent(const unsigned* p) {
  return __hip_atomic_load(p, __ATOMIC_RELAXED, __HIP_MEMORY_SCOPE_AGENT);
}

// ---------------- elementwise converts / init ----------------

__global__ void f32_to_bf16_k(const float* __restrict__ s, u16* __restrict__ d, int n) {
  int stride = gridDim.x * blockDim.x * 4;
  for (int i = (blockIdx.x * blockDim.x + threadIdx.x) * 4; i < n; i += stride) {
    float4 v = *(const float4*)(s + i);
    uint2 p;
    p.x = (unsigned)f2b(v.x) | ((unsigned)f2b(v.y) << 16);
    p.y = (unsigned)f2b(v.z) | ((unsigned)f2b(v.w) << 16);
    *(uint2*)(d + i) = p;
  }
}

__global__ void init_h_k(const float* __restrict__ h0in, u16* __restrict__ hbuf0,
                         u16* __restrict__ hbuf1) {
  int i = blockIdx.x * blockDim.x + threadIdx.x;
  if (i < BB * HH) {
    hbuf0[i] = f2b(h0in[i]);            // slot 0 = H0(0)
    hbuf1[i] = f2b(h0in[BB * HH + i]);  // slot 0 = H1(0)
  }
}

// ---------------- phase A: xg0 = bf16(x @ W_ih0^T + b_ih0) ----------------

__global__ __launch_bounds__(256) void gemm_xg_k(
    const u16* __restrict__ A, const u16* __restrict__ Wt,
    const float* __restrict__ bias, u16* __restrict__ C) {
  const int bm = blockIdx.x / 24;
  const int bn = blockIdx.x % 24;
  const int m0 = bm * 128, n0 = bn * 128;
  __shared__ __align__(16) u16 al[128 * 40];
  __shared__ __align__(16) u16 bl[128 * 40];
  const int tid = threadIdx.x;
  const int w = tid >> 6, l = tid & 63;
  const int wr = w >> 1, wc = w & 1;
  const int c0 = tid, c1 = tid + 256;
  const int r0 = c0 >> 2, s0 = c0 & 3, r1 = c1 >> 2, s1 = c1 & 3;

  const f32x4 fzero = {0.f, 0.f, 0.f, 0.f};
  f32x4 acc[4][4];
#pragma unroll
  for (int i = 0; i < 4; ++i)
#pragma unroll
    for (int j = 0; j < 4; ++j) acc[i][j] = fzero;

  const u16* a0p = A + (size_t)(m0 + r0) * 1024 + s0 * 8;
  const u16* a1p = A + (size_t)(m0 + r1) * 1024 + s1 * 8;
  const u16* b0p = Wt + (size_t)(n0 + r0) * 1024 + s0 * 8;
  const u16* b1p = Wt + (size_t)(n0 + r1) * 1024 + s1 * 8;

  int4 va0 = *(const int4*)(a0p);
  int4 va1 = *(const int4*)(a1p);
  int4 vb0 = *(const int4*)(b0p);
  int4 vb1 = *(const int4*)(b1p);

  for (int kt = 0; kt < 32; ++kt) {
    __syncthreads();
    *(int4*)&al[r0 * 40 + s0 * 8] = va0;
    *(int4*)&al[r1 * 40 + s1 * 8] = va1;
    *(int4*)&bl[r0 * 40 + s0 * 8] = vb0;
    *(int4*)&bl[r1 * 40 + s1 * 8] = vb1;
    __syncthreads();
    if (kt < 31) {
      va0 = *(const int4*)(a0p + (kt + 1) * 32);
      va1 = *(const int4*)(a1p + (kt + 1) * 32);
      vb0 = *(const int4*)(b0p + (kt + 1) * 32);
      vb1 = *(const int4*)(b1p + (kt + 1) * 32);
    }
    short8 af[4], bf[4];
#pragma unroll
    for (int i = 0; i < 4; ++i)
      af[i] = *(const short8*)&al[(wr * 64 + i * 16 + (l & 15)) * 40 + (l >> 4) * 8];
#pragma unroll
    for (int j = 0; j < 4; ++j)
      bf[j] = *(const short8*)&bl[(wc * 64 + j * 16 + (l & 15)) * 40 + (l >> 4) * 8];
#pragma unroll
    for (int i = 0; i < 4; ++i)
#pragma unroll
      for (int j = 0; j < 4; ++j)
        acc[i][j] = __builtin_amdgcn_mfma_f32_16x16x32_bf16(af[i], bf[j], acc[i][j], 0, 0, 0);
  }

#pragma unroll
  for (int i = 0; i < 4; ++i) {
#pragma unroll
    for (int j = 0; j < 4; ++j) {
      int col = n0 + wc * 64 + j * 16 + (l & 15);
      float bv = bias[col];
#pragma unroll
      for (int q = 0; q < 4; ++q) {
        int row = m0 + wr * 64 + i * 16 + (l >> 4) * 4 + q;
        C[(size_t)row * G3 + col] = f2b(acc[i][j][q] + bv);
      }
    }
  }
}

// ---------------- persistent fused scan, v8 ----------------
// Renamed h buffers (R8-proven: sc1 writes -> LLC; renamed normal cached
// reads). Part1 merged into part2: each layer-1 block computes its own xg1
// on the fly (ih GEMM vs hbuf0[t]) + h-update (hh GEMM vs hbuf1[t-1]).
// Barrier: padded per-block flag lines (128B apart) + s_sleep backoff.
//  part0 (blk 0..63, 16 cols): layer0 step t (t<=511): reads hbuf0[t],
//        writes hbuf0[t+1]
//  part2 (blk 64..191, 8 cols): layer1 step t-1 (t>=1): reads hbuf1[t-1]
//        + hbuf0[t], writes hbuf1[t]

__global__ __launch_bounds__(256, 1) void gru_scan8_k(
    const u16* __restrict__ xg0,
    const u16* __restrict__ whh0, const u16* __restrict__ wih1,
    const u16* __restrict__ whh1,
    const float* __restrict__ bhh0, const float* __restrict__ bih1,
    const float* __restrict__ bhh1,
    const float* __restrict__ h0in,
    u16* __restrict__ hbuf0, u16* __restrict__ hbuf1,
    float* __restrict__ out, unsigned* __restrict__ flags) {
  const int blk = blockIdx.x;
  const int part0 = (blk < 64);
  const int tid = threadIdx.x;
  const int w = tid >> 6, l = tid & 63;
  const int lrow = l & 15;
  const int lr7 = lrow & 7;
  const int kb = (l >> 4) * 8;
  const int myrow0 = w * 16 + (l >> 4) * 4;  // batch rows myrow0..+3
  const size_t arow = (size_t)(w * 16 + lrow) * HH + kb;
  const f32x4 fzero = {0.f, 0.f, 0.f, 0.f};

  // LDS: part0: whh0 48 rows (96KB). part2: whh1 24 rows + wih1 24 rows
  // (rows g*8+(0..7) per gate; fragment rows 8..15 alias 0..7).
  __shared__ __align__(16) u16 wlds[48 * 1024];

  int j;           // this lane's output column
  float hreg[4] = {0.f, 0.f, 0.f, 0.f};
  float bhr = 0.f, bhz = 0.f, bhn = 0.f;   // b_hh gates
  float bir = 0.f, biz = 0.f, bin = 0.f;   // b_ih gates (part2 only)
  bool valid;      // lane owns a real column

  if (part0) {
    const int sub = blk;
    j = sub * 16 + lrow;
    valid = true;
    for (int i = tid; i < 6144; i += 256) {
      int r = i >> 7;
      int c = i & 127;
      int g = r >> 4;
      int wrow = g * HH + sub * 16 + (r & 15);
      int4 v = *(const int4*)(whh0 + (size_t)wrow * 1024 + c * 8);
      int idx = r * 1024 + ((c * 8) ^ ((r & 7) << 3));
      *(int4*)&wlds[idx] = v;
    }
    bhr = bhh0[j]; bhz = bhh0[HH + j]; bhn = bhh0[2 * HH + j];
#pragma unroll
    for (int q = 0; q < 4; ++q) hreg[q] = h0in[(myrow0 + q) * HH + j];
  } else {
    const int sub = blk - 64;
    valid = (lrow < 8);
    j = sub * 8 + (valid ? lrow : 0);   // clamp inactive lanes in-range
    // rows 0..23 = whh1 (3 gates x 8), rows 24..47 = wih1 (3 gates x 8)
    for (int i = tid; i < 6144; i += 256) {
      int r = i >> 7;
      int c = i & 127;
      int half = r >= 24;
      int rr = half ? r - 24 : r;
      int g = rr >> 3;
      const u16* src = half ? wih1 : whh1;
      int wrow = g * HH + sub * 8 + (rr & 7);
      int4 v = *(const int4*)(src + (size_t)wrow * 1024 + c * 8);
      int idx = r * 1024 + ((c * 8) ^ ((r & 7) << 3));
      *(int4*)&wlds[idx] = v;
    }
    bhr = bhh1[j]; bhz = bhh1[HH + j]; bhn = bhh1[2 * HH + j];
    bir = bih1[j]; biz = bih1[HH + j]; bin = bih1[2 * HH + j];
#pragma unroll
    for (int q = 0; q < 4; ++q) hreg[q] = h0in[BB * HH + (myrow0 + q) * HH + j];
  }
  __syncthreads();

  const int sx = lr7 << 3;  // swizzle: elem idx ^= (row&7)<<3

  for (int t = 0; t <= 512; ++t) {
    if (part0) {
      if (t <= 511) {
        const u16* Ap = hbuf0 + (size_t)t * SLOT + arow;
        short8 ar[32];
#pragma unroll
        for (int ks = 0; ks < 32; ++ks) ar[ks] = *(const short8*)(Ap + ks * 32);

        u16 xrv[4], xzv[4], xnv[4];
        const u16* xp = xg0 + (size_t)t * BB * G3;
#pragma unroll
        for (int q = 0; q < 4; ++q) {
          const u16* rp = xp + (size_t)(myrow0 + q) * G3;
          xrv[q] = rp[j]; xzv[q] = rp[HH + j]; xnv[q] = rp[2 * HH + j];
        }

        f32x4 acc0 = fzero, acc1 = fzero, acc2 = fzero;
#pragma unroll
        for (int ks = 0; ks < 32; ++ks) {
          int ke = kb + ks * 32;
          short8 b0 = *(const short8*)&wlds[(lrow) * 1024 + (ke ^ sx)];
          short8 b1 = *(const short8*)&wlds[(16 + lrow) * 1024 + (ke ^ sx)];
          short8 b2 = *(const short8*)&wlds[(32 + lrow) * 1024 + (ke ^ sx)];
          acc0 = __builtin_amdgcn_mfma_f32_16x16x32_bf16(ar[ks], b0, acc0, 0, 0, 0);
          acc1 = __builtin_amdgcn_mfma_f32_16x16x32_bf16(ar[ks], b1, acc1, 0, 0, 0);
          acc2 = __builtin_amdgcn_mfma_f32_16x16x32_bf16(ar[ks], b2, acc2, 0, 0, 0);
        }

        u16* hbn = hbuf0 + (size_t)(t + 1) * SLOT;
#pragma unroll
        for (int q = 0; q < 4; ++q) {
          float rr = acc0[q] + bhr + b2f(xrv[q]);
          float zz = acc1[q] + bhz + b2f(xzv[q]);
          float nn = acc2[q] + bhn;
          float r = 1.f / (1.f + __expf(-rr));
          float z = 1.f / (1.f + __expf(-zz));
          float n = tanhf(b2f(xnv[q]) + r * nn);
          float hv = (1.f - z) * n + z * hreg[q];
          hreg[q] = hv;
          int hb = (int)f2b(hv);
          int nb = __shfl_xor(hb, 1);
          if ((l & 1) == 0) {
            unsigned pk = (unsigned)(u16)hb | (((unsigned)(u16)nb) << 16);
            st_u32_agent((unsigned*)(hbn + (size_t)(myrow0 + q) * HH + j), pk);
          }
        }
      }
    } else {
      if (t >= 1) {
        // ---- ih GEMM: xg1 = hbuf0[t] @ W_ih1 slice ----
        const u16* Ai = hbuf0 + (size_t)t * SLOT + arow;
        short8 ar[32];
#pragma unroll
        for (int ks = 0; ks < 32; ++ks) ar[ks] = *(const short8*)(Ai + ks * 32);
        f32x4 xri = fzero, xzi = fzero, xni = fzero;
#pragma unroll
        for (int ks = 0; ks < 32; ++ks) {
          int ke = kb + ks * 32;
          short8 b0 = *(const short8*)&wlds[(24 + lr7) * 1024 + (ke ^ sx)];
          short8 b1 = *(const short8*)&wlds[(32 + lr7) * 1024 + (ke ^ sx)];
          short8 b2 = *(const short8*)&wlds[(40 + lr7) * 1024 + (ke ^ sx)];
          xri = __builtin_amdgcn_mfma_f32_16x16x32_bf16(ar[ks], b0, xri, 0, 0, 0);
          xzi = __builtin_amdgcn_mfma_f32_16x16x32_bf16(ar[ks], b1, xzi, 0, 0, 0);
          xni = __builtin_amdgcn_mfma_f32_16x16x32_bf16(ar[ks], b2, xni, 0, 0, 0);
        }
        // ---- hh GEMM: hbuf1[t-1] @ W_hh1 slice ----
        const u16* Ah = hbuf1 + (size_t)(t - 1) * SLOT + arow;
#pragma unroll
        for (int ks = 0; ks < 32; ++ks) ar[ks] = *(const short8*)(Ah + ks * 32);
        f32x4 hri = fzero, hzi = fzero, hni = fzero;
#pragma unroll
        for (int ks = 0; ks < 32; ++ks) {
          int ke = kb + ks * 32;
          short8 b0 = *(const short8*)&wlds[(0 + lr7) * 1024 + (ke ^ sx)];
          short8 b1 = *(const short8*)&wlds[(8 + lr7) * 1024 + (ke ^ sx)];
          short8 b2 = *(const short8*)&wlds[(16 + lr7) * 1024 + (ke ^ sx)];
          hri = __builtin_amdgcn_mfma_f32_16x16x32_bf16(ar[ks], b0, hri, 0, 0, 0);
          hzi = __builtin_amdgcn_mfma_f32_16x16x32_bf16(ar[ks], b1, hzi, 0, 0, 0);
          hni = __builtin_amdgcn_mfma_f32_16x16x32_bf16(ar[ks], b2, hni, 0, 0, 0);
        }

        u16* hbn = hbuf1 + (size_t)t * SLOT;
#pragma unroll
        for (int q = 0; q < 4; ++q) {
          float rr = (xri[q] + bir) + (hri[q] + bhr);
          float zz = (xzi[q] + biz) + (hzi[q] + bhz);
          float nn = hni[q] + bhn;
          float r = 1.f / (1.f + __expf(-rr));
          float z = 1.f / (1.f + __expf(-zz));
          float n = tanhf((xni[q] + bin) + r * nn);
          float hv = (1.f - z) * n + z * hreg[q];
          hreg[q] = hv;
          int hb = (int)f2b(hv);
          int nb = __shfl_xor(hb, 1);
          if (valid && (l & 1) == 0) {
            unsigned pk = (unsigned)(u16)hb | (((unsigned)(u16)nb) << 16);
            st_u32_agent((unsigned*)(hbn + (size_t)(myrow0 + q) * HH + j), pk);
          }
        }
      }
    }

    // ---- grid barrier: padded flag lines + wave0 poll + backoff ----
    __syncthreads();  // all waves' sc1 stores vmcnt-drained (ack'd at LLC)
    if (tid == 0) {
      __builtin_amdgcn_fence(__ATOMIC_RELEASE, "workgroup");
      st_u32_agent(&flags[blk * FSTRIDE], (unsigned)(t + 1));
    }
    if (tid < 64) {
      const unsigned tgt = (unsigned)(t + 1);
      for (;;) {
        unsigned a0 = ld_u32_agent(&flags[l * FSTRIDE]);
        unsigned a1 = ld_u32_agent(&flags[(l + 64) * FSTRIDE]);
        unsigned a2 = ld_u32_agent(&flags[(l + 128) * FSTRIDE]);
        unsigned mn = a0 < a1 ? a0 : a1;
        mn = mn < a2 ? mn : a2;
        if (__all(mn >= tgt)) break;
        __builtin_amdgcn_s_sleep(2);
      }
    }
    __syncthreads();
    __builtin_amdgcn_fence(__ATOMIC_ACQUIRE, "workgroup");
  }

  // ---- write h_n ----
  if (part0) {
#pragma unroll
    for (int q = 0; q < 4; ++q) out[(size_t)(myrow0 + q) * HH + j] = hreg[q];
  } else if (valid) {
#pragma unroll
    for (int q = 0; q < 4; ++q) out[BB * HH + (size_t)(myrow0 + q) * HH + j] = hreg[q];
  }
}

// ---------------- host ----------------

extern "C" void kernel_launch(void* const* d_in, const int* in_sizes, int n_in,
                              void* d_out, int out_size, void* d_ws, size_t ws_size,
                              hipStream_t stream) {
  const float* x   = (const float*)d_in[0];
  const float* h0  = (const float*)d_in[1];
  const float* wih = (const float*)d_in[2];
  const float* whh = (const float*)d_in[3];
  const float* bih = (const float*)d_in[4];
  const float* bhh = (const float*)d_in[5];
  float* out = (float*)d_out;

  char* ws = (char*)d_ws;
  size_t off = 0;
  auto alloc = [&](size_t bytes) -> void* {
    void* p = ws + off;
    off += (bytes + 255) & ~(size_t)255;
    return p;
  };
  u16* xg0   = (u16*)alloc((size_t)TT * BB * G3 * 2);        // 193 MB
  u16* wihb  = (u16*)alloc((size_t)2 * G3 * HH * 2);         // 12.6 MB
  u16* whhb  = (u16*)alloc((size_t)2 * G3 * HH * 2);         // 12.6 MB
  // union: xbf (64 MB, dead after gemm) overlaid by hbuf0/hbuf1 (134.5 MB)
  size_t hbytes = (size_t)2 * NS * SLOT * 2;
  size_t xbytes = (size_t)TT * BB * HH * 2;
  char* un = (char*)alloc(hbytes > xbytes ? hbytes : xbytes);
  u16* xbf   = (u16*)un;
  u16* hbuf0 = (u16*)un;
  u16* hbuf1 = hbuf0 + (size_t)NS * SLOT;
  unsigned* flags = (unsigned*)alloc(NBLK * FSTRIDE * 4);

  hipMemsetAsync(flags, 0, NBLK * FSTRIDE * 4, stream);
  f32_to_bf16_k<<<2048, 256, 0, stream>>>(x, xbf, TT * BB * HH);
  f32_to_bf16_k<<<512, 256, 0, stream>>>(wih, wihb, 2 * G3 * HH);
  f32_to_bf16_k<<<512, 256, 0, stream>>>(whh, whhb, 2 * G3 * HH);

  gemm_xg_k<<<6144, 256, 0, stream>>>(xbf, wihb, bih, xg0);

  // init h AFTER gemm: hbuf aliases xbf
  init_h_k<<<256, 256, 0, stream>>>(h0, hbuf0, hbuf1);

  gru_scan8_k<<<NBLK, 256, 0, stream>>>(xg0,
                                        whhb, wihb + (size_t)G3 * HH, whhb + (size_t)G3 * HH,
                                        bhh, bih + G3, bhh + G3, h0,
                                        hbuf0, hbuf1, out, flags);
}